// Round 2
// baseline (6711.439 us; speedup 1.0000x reference)
//
#include <hip/hip_runtime.h>

typedef _Float16 half8 __attribute__((ext_vector_type(8)));
typedef float floatx4 __attribute__((ext_vector_type(4)));
typedef unsigned int u32;
typedef unsigned long long u64;
typedef u64 u64x2 __attribute__((ext_vector_type(2)));

#define T_SEQ 4096
#define EMBD  512
#define HID   1024
#define G4    4096   /* 4*HID */
#define NWG   64     /* recurrence workgroups */

/* ---------------- helpers ---------------- */

__device__ __forceinline__ void stage16(const void* g, void* l) {
  __builtin_amdgcn_global_load_lds((const __attribute__((address_space(1))) u32*)g,
                                   (__attribute__((address_space(3))) u32*)l, 16, 0, 0);
}

__device__ __forceinline__ float fsigmoid(float x) {
  return 1.f / (1.f + __expf(-x));
}
__device__ __forceinline__ float ftanh(float x) {
  x = fminf(fmaxf(x, -15.f), 15.f);
  float e = __expf(2.f * x);
  return (e - 1.f) / (e + 1.f);
}

/* ---------------- phase 0: convert / gather / init ---------------- */

__global__ __launch_bounds__(256) void prep_kernel(
    const float* __restrict__ Whh, const float* __restrict__ Wih,
    const float* __restrict__ emb, const int* __restrict__ words,
    const float* __restrict__ bih, const float* __restrict__ bhh,
    _Float16* __restrict__ whh_h, _Float16* __restrict__ wih_h,
    _Float16* __restrict__ xh, float* __restrict__ biasf, u64* __restrict__ hg) {
  const long long S1 = (long long)G4 * HID;     // 4194304
  const long long S2 = (long long)G4 * EMBD;    // 2097152
  const long long S3 = (long long)T_SEQ * EMBD; // 2097152
  const long long S4 = G4;
  const long long S5 = 1024;                    // 2 x 512 tagged h packets
  const long long tot = S1 + S2 + S3 + S4 + S5;
  long long stride = (long long)gridDim.x * blockDim.x;
  for (long long i = (long long)blockIdx.x * blockDim.x + threadIdx.x; i < tot; i += stride) {
    long long j = i;
    if (j < S1) { whh_h[j] = (_Float16)Whh[j]; continue; }
    j -= S1;
    if (j < S2) { wih_h[j] = (_Float16)Wih[j]; continue; }
    j -= S2;
    if (j < S3) {
      int t = (int)(j >> 9), e = (int)(j & 511);
      xh[j] = (_Float16)emb[(long long)words[t] * EMBD + e];
      continue;
    }
    j -= S3;
    if (j < S4) { biasf[j] = bih[j] + bhh[j]; continue; }
    j -= S4;
    hg[j] = 0ull;   // tag 0, h = fp16 zeros
  }
}

/* ---------------- phase 1: xg = x @ Wih^T + bias, column-permuted ----------
   Source col n = g*1024 + r  (g = gate, r = h-row) stored at
   np = (r>>4)*64 + ((r>>2)&3)*16 + (r&3)*4 + g
   so that lane l of wave w in WG wg reads xg_p[s][wg*64 + w*16 + l]. */

__global__ __launch_bounds__(256) void xg_gemm(
    const _Float16* __restrict__ A, const _Float16* __restrict__ B,
    const float* __restrict__ biasf, float* __restrict__ C) {
  __shared__ char smem[2][2][8192];
  const int tid = threadIdx.x;
  const int lane = tid & 63;
  const int wid = tid >> 6;
  const int wy = wid >> 1, wx = wid & 1;
  const int tm = blockIdx.x * 128, tn = blockIdx.y * 128;

  floatx4 acc[4][4];
#pragma unroll
  for (int a = 0; a < 4; a++)
#pragma unroll
    for (int b = 0; b < 4; b++) acc[a][b] = (floatx4){0.f, 0.f, 0.f, 0.f};

  auto stage = [&](int buf, int kb) {
#pragma unroll
    for (int ii = 0; ii < 2; ii++) {
      int ci = tid + ii * 256;        // 0..511 chunks of 16B
      int r = ci >> 2, cs = ci & 3;
      int c = cs ^ (r & 3);           // inverse-swizzled source slot
      const _Float16* srcA = A + (long long)(tm + r) * EMBD + kb + c * 8;
      const _Float16* srcB = B + (long long)(tn + r) * EMBD + kb + c * 8;
      char* ldsA = &smem[buf][0][(ci & ~63) << 4];   // wave-uniform base
      char* ldsB = &smem[buf][1][(ci & ~63) << 4];
      stage16(srcA, ldsA);
      stage16(srcB, ldsB);
    }
  };

  stage(0, 0);
  __syncthreads();

  for (int t = 0; t < 16; t++) {
    int cur = t & 1;
    if (t < 15) stage(cur ^ 1, (t + 1) * 32);   // async, in flight during compute
    const char* As = smem[cur][0];
    const char* Bs = smem[cur][1];
    const int kc = lane >> 4;
    half8 af[4], bfr[4];
#pragma unroll
    for (int am = 0; am < 4; am++) {
      int r = wy * 64 + am * 16 + (lane & 15);
      af[am] = *(const half8*)(As + r * 64 + ((kc ^ (r & 3)) << 4));
    }
#pragma unroll
    for (int bn = 0; bn < 4; bn++) {
      int r = wx * 64 + bn * 16 + (lane & 15);
      bfr[bn] = *(const half8*)(Bs + r * 64 + ((kc ^ (r & 3)) << 4));
    }
#pragma unroll
    for (int am = 0; am < 4; am++)
#pragma unroll
      for (int bn = 0; bn < 4; bn++)
        acc[am][bn] = __builtin_amdgcn_mfma_f32_16x16x32_f16(af[am], bfr[bn], acc[am][bn], 0, 0, 0);
    __syncthreads();
  }

#pragma unroll
  for (int am = 0; am < 4; am++) {
    int mrow = tm + wy * 64 + am * 16 + (lane >> 4) * 4;
#pragma unroll
    for (int bn = 0; bn < 4; bn++) {
      int n = tn + wx * 64 + bn * 16 + (lane & 15);
      int r = n & 1023, g = n >> 10;
      int np = ((r >> 4) << 6) + (((r >> 2) & 3) << 4) + ((r & 3) << 2) + g;
      float bias = biasf[n];
#pragma unroll
      for (int rg = 0; rg < 4; rg++)
        C[(long long)(mrow + rg) * G4 + np] = acc[am][bn][rg] + bias;
    }
  }
}

/* ---------------- phase 2: persistent forward LSTM recurrence ----------------
   64 WGs x 256 threads (4 waves). WG wg owns h[wg*16 .. wg*16+16).
   Wave w: 16 gate-cols = {gate l&3, row wg*16 + w*4 + (l>>2)}, FULL K=1024
   (32 MFMAs, 4 interleaved chains). Activation in-wave via shfl; lanes 0,8
   publish {tag, 2 x fp16 h} u64 packets. 512 packets total; each thread polls
   2 via one 16B sc1 load (atomic-load fallback for safety). */

__global__ __launch_bounds__(256, 1) void lstm_fwd(
    const _Float16* __restrict__ Whh_h, const float* __restrict__ xg,
    u64* __restrict__ hg) {
  __shared__ u32 hp[512];       // 1024 packed fp16 h values
  const int tid = threadIdx.x;
  const int lane = tid & 63;
  const int w = tid >> 6;       // wave 0..3
  const int wg = blockIdx.x;
  const int n = lane & 15;
  const int kc = lane >> 4;

  // persistent B fragments: col n -> Whh row R, full K
  const int R = (n & 3) * HID + wg * 16 + w * 4 + (n >> 2);
  half8 Wb[32];
  {
    const _Float16* wr = Whh_h + (long long)R * HID + kc * 8;
#pragma unroll
    for (int kk = 0; kk < 32; kk++)
      Wb[kk] = *(const half8*)(wr + kk * 32);
  }

  u64* h0 = hg;
  u64* h1 = hg + 512;
  float c = 0.f;

  const float* xbase = xg + wg * 64 + w * 16 + lane;  // used by lanes < 16
  float xv_cur = 0.f, xv_nxt = 0.f;
  if (lane < 16) xv_cur = xbase[0];

  for (int s = 0; s < T_SEQ; s++) {
    const u64* src = (s & 1) ? h1 : h0;
    u64* dst = (s & 1) ? h0 : h1;

    // ---- poll our 2 packets (one 16B load; fallback path every 16 spins) ----
    {
      const u64* p = src + 2 * tid;
      const u32 want = (u32)s;
      u64 e0, e1;
      int spins = 0;
      for (;;) {
        u64x2 v;
        asm volatile("global_load_dwordx4 %0, %1, off sc1\n\ts_waitcnt vmcnt(0)"
                     : "=v"(v) : "v"(p) : "memory");
        if ((u32)(v.x >> 32) == want && (u32)(v.y >> 32) == want) { e0 = v.x; e1 = v.y; break; }
        if ((++spins & 15) == 0) {
          u64 a = __hip_atomic_load(p,     __ATOMIC_RELAXED, __HIP_MEMORY_SCOPE_AGENT);
          u64 b = __hip_atomic_load(p + 1, __ATOMIC_RELAXED, __HIP_MEMORY_SCOPE_AGENT);
          if ((u32)(a >> 32) == want && (u32)(b >> 32) == want) { e0 = a; e1 = b; break; }
        }
      }
      *reinterpret_cast<u64*>(&hp[2 * tid]) = ((u64)(u32)e1 << 32) | (u64)(u32)e0;
    }

    // prefetch next step's xg element (overlaps MFMA+act; used next iteration)
    if (lane < 16 && s + 1 < T_SEQ) xv_nxt = xbase[(long long)(s + 1) * G4];

    __syncthreads();

    // ---- matvec: 32 MFMAs, 4 interleaved chains; A = h broadcast ----
    floatx4 ac0 = (floatx4){0.f,0.f,0.f,0.f};
    floatx4 ac1 = (floatx4){0.f,0.f,0.f,0.f};
    floatx4 ac2 = (floatx4){0.f,0.f,0.f,0.f};
    floatx4 ac3 = (floatx4){0.f,0.f,0.f,0.f};
    const char* hh = (const char*)hp;
#pragma unroll
    for (int kb = 0; kb < 8; kb++) {
      half8 a0 = *(const half8*)(hh + (kb * 4 + 0) * 64 + kc * 16);
      half8 a1 = *(const half8*)(hh + (kb * 4 + 1) * 64 + kc * 16);
      half8 a2 = *(const half8*)(hh + (kb * 4 + 2) * 64 + kc * 16);
      half8 a3 = *(const half8*)(hh + (kb * 4 + 3) * 64 + kc * 16);
      ac0 = __builtin_amdgcn_mfma_f32_16x16x32_f16(a0, Wb[kb * 4 + 0], ac0, 0, 0, 0);
      ac1 = __builtin_amdgcn_mfma_f32_16x16x32_f16(a1, Wb[kb * 4 + 1], ac1, 0, 0, 0);
      ac2 = __builtin_amdgcn_mfma_f32_16x16x32_f16(a2, Wb[kb * 4 + 2], ac2, 0, 0, 0);
      ac3 = __builtin_amdgcn_mfma_f32_16x16x32_f16(a3, Wb[kb * 4 + 3], ac3, 0, 0, 0);
    }
    float gv = ac0[0] + ac1[0] + ac2[0] + ac3[0] + xv_cur;

    // ---- in-wave activation: col l = (gate l&3, row base w*4 + (l>>2)) ----
    float a = ((lane & 3) == 2) ? ftanh(gv) : fsigmoid(gv);
    int base = lane & ~3;
    float i_ = __shfl(a, base + 0);
    float f_ = __shfl(a, base + 1);
    float g_ = __shfl(a, base + 2);
    float o_ = __shfl(a, base + 3);
    c = f_ * c + i_ * g_;           // valid in lanes 0,4,8,12
    float hn = o_ * ftanh(c);

    union { _Float16 hx[2]; u32 u; } pk;
    pk.hx[0] = (_Float16)hn; pk.hx[1] = (_Float16)0.f;
    u32 bits = pk.u & 0xffffu;
    u32 nbr = (u32)__shfl((int)bits, lane | 4);   // lane0<-lane4, lane8<-lane12
    if (lane < 16 && (lane & 7) == 0) {
      u64 pkt = ((u64)(u32)(s + 1) << 32) | (u64)(bits | ((nbr & 0xffffu) << 16));
      __hip_atomic_store(&dst[wg * 8 + w * 2 + (lane >> 3)], pkt,
                         __ATOMIC_RELAXED, __HIP_MEMORY_SCOPE_AGENT);
    }
    __syncthreads();   // protect hp before next step's poll writes
    xv_cur = xv_nxt;
  }
}

/* ---------------- phase 3: backward direction = ONE cell step on x[T-1] ------- */

__global__ __launch_bounds__(256) void bwd_gates(
    const float* __restrict__ Wihb, const float* __restrict__ emb,
    const int* __restrict__ words, const float* __restrict__ bihb,
    const float* __restrict__ bhhb, float* __restrict__ gb) {
  const int row = blockIdx.x * 4 + (threadIdx.x >> 6);
  const int lane = threadIdx.x & 63;
  const long long wl = words[T_SEQ - 1];
  const float* xr = emb + wl * EMBD;
  const float* wr = Wihb + (long long)row * EMBD;
  const int k0 = lane * 8;
  float s = 0.f;
#pragma unroll
  for (int j = 0; j < 8; j += 4) {
    float4 wv = *(const float4*)(wr + k0 + j);
    float4 xv = *(const float4*)(xr + k0 + j);
    s += wv.x * xv.x + wv.y * xv.y + wv.z * xv.z + wv.w * xv.w;
  }
#pragma unroll
  for (int m = 1; m < 64; m <<= 1) s += __shfl_xor(s, m);
  if (lane == 0) gb[row] = s + bihb[row] + bhhb[row];
}

/* ---------------- phase 4: backward activations + projection ---------------- */

__global__ __launch_bounds__(256) void final_k(
    const u64* __restrict__ hg, const float* __restrict__ gb,
    const float* __restrict__ Wp, const float* __restrict__ bp,
    float* __restrict__ out) {
  __shared__ float last[2 * HID];
  __shared__ float red[4];
  const int tid = threadIdx.x;
  // h_T sits in parity-0 buffer as 512 {tag, 2xfp16} packets
  for (int p = tid; p < 512; p += 256) {
    u32 b = (u32)hg[p];
    union { unsigned short s; _Float16 h; } lo, hi;
    lo.s = (unsigned short)(b & 0xffffu);
    hi.s = (unsigned short)(b >> 16);
    last[2 * p]     = (float)lo.h;
    last[2 * p + 1] = (float)hi.h;
  }
  for (int j = tid; j < HID; j += 256) {
    float i_ = fsigmoid(gb[j]);
    float g_ = ftanh(gb[2 * HID + j]);
    float o_ = fsigmoid(gb[3 * HID + j]);
    float cb = i_ * g_;                              // c0 = 0, f-gate irrelevant
    last[HID + j] = o_ * ftanh(cb);
  }
  __syncthreads();
  const int lane = tid & 63, wv = tid >> 6;
  for (int nn = 0; nn < 5; nn++) {
    float p = 0.f;
    for (int j = tid; j < 2 * HID; j += 256) p += last[j] * Wp[nn * 2 * HID + j];
#pragma unroll
    for (int m = 1; m < 64; m <<= 1) p += __shfl_xor(p, m);
    if (lane == 0) red[wv] = p;
    __syncthreads();
    if (tid == 0) out[nn] = red[0] + red[1] + red[2] + red[3] + bp[nn];
    __syncthreads();
  }
}

/* ---------------- launcher ---------------- */

extern "C" void kernel_launch(void* const* d_in, const int* in_sizes, int n_in,
                              void* d_out, int out_size, void* d_ws, size_t ws_size,
                              hipStream_t stream) {
  const int*   words = (const int*)d_in[0];
  const float* emb   = (const float*)d_in[1];
  const float* Wih_f = (const float*)d_in[2];
  const float* Whh_f = (const float*)d_in[3];
  const float* bih_f = (const float*)d_in[4];
  const float* bhh_f = (const float*)d_in[5];
  const float* Wih_b = (const float*)d_in[6];
  /* d_in[7] = Whh_b: unused — backward direction is a single step from zero state */
  const float* bih_b = (const float*)d_in[8];
  const float* bhh_b = (const float*)d_in[9];
  const float* Wp    = (const float*)d_in[10];
  const float* bp    = (const float*)d_in[11];
  float* out = (float*)d_out;

  char* ws = (char*)d_ws;
  float*    XG    = (float*)(ws);                    // [T,4H] f32, col-permuted: 64 MB
  _Float16* WHH   = (_Float16*)(ws + 67108864);      // [4H,H] fp16: 8 MB
  _Float16* WIH   = (_Float16*)(ws + 75497472);      // [4H,E] fp16: 4 MB
  _Float16* XH    = (_Float16*)(ws + 79691776);      // [T,E]  fp16: 4 MB
  u64*      HG    = (u64*)(ws + 83886080);           // 2 x 512 tagged h packets: 8 KB
  float*    GB    = (float*)(ws + 83902464);         // backward gates: 16 KB
  float*    BIASF = (float*)(ws + 83918848);         // bih_f + bhh_f: 16 KB

  prep_kernel<<<2048, 256, 0, stream>>>(Whh_f, Wih_f, emb, words, bih_f, bhh_f,
                                        WHH, WIH, XH, BIASF, HG);
  xg_gemm<<<dim3(32, 32), 256, 0, stream>>>(XH, WIH, BIASF, XG);
  lstm_fwd<<<NWG, 256, 0, stream>>>(WHH, XG, HG);
  bwd_gates<<<1024, 256, 0, stream>>>(Wih_b, emb, words, bih_b, bhh_b, GB);
  final_k<<<1, 256, 0, stream>>>(HG, GB, Wp, bp, out);
}

// Round 3
// 6227.369 us; speedup vs baseline: 1.0777x; 1.0777x over previous
//
#include <hip/hip_runtime.h>

typedef _Float16 half8 __attribute__((ext_vector_type(8)));
typedef float floatx4 __attribute__((ext_vector_type(4)));
typedef unsigned int u32;
typedef unsigned long long u64;
typedef u64 u64x2 __attribute__((ext_vector_type(2)));

#define T_SEQ 4096
#define EMBD  512
#define HID   1024
#define G4    4096   /* 4*HID */
#define NWG   64     /* recurrence workgroups */

/* ---------------- helpers ---------------- */

__device__ __forceinline__ void stage16(const void* g, void* l) {
  __builtin_amdgcn_global_load_lds((const __attribute__((address_space(1))) u32*)g,
                                   (__attribute__((address_space(3))) u32*)l, 16, 0, 0);
}

__device__ __forceinline__ float frcp(float x) {
#if __has_builtin(__builtin_amdgcn_rcpf)
  return __builtin_amdgcn_rcpf(x);
#else
  return 1.f / x;
#endif
}

__device__ __forceinline__ float fsigmoid(float x) {
  return frcp(1.f + __expf(-x));
}
__device__ __forceinline__ float ftanh(float x) {
  return fmaf(2.f, frcp(1.f + __expf(-2.f * x)), -1.f);
}

/* ---------------- phase 0: convert / gather / init ---------------- */

__global__ __launch_bounds__(256) void prep_kernel(
    const float* __restrict__ Whh, const float* __restrict__ Wih,
    const float* __restrict__ emb, const int* __restrict__ words,
    const float* __restrict__ bih, const float* __restrict__ bhh,
    _Float16* __restrict__ whh_h, _Float16* __restrict__ wih_h,
    _Float16* __restrict__ xh, float* __restrict__ biasf, u64* __restrict__ hg) {
  const long long S1 = (long long)G4 * HID;     // 4194304
  const long long S2 = (long long)G4 * EMBD;    // 2097152
  const long long S3 = (long long)T_SEQ * EMBD; // 2097152
  const long long S4 = G4;
  const long long S5 = 1024;                    // 2 x 512 tagged h packets
  const long long tot = S1 + S2 + S3 + S4 + S5;
  long long stride = (long long)gridDim.x * blockDim.x;
  for (long long i = (long long)blockIdx.x * blockDim.x + threadIdx.x; i < tot; i += stride) {
    long long j = i;
    if (j < S1) { whh_h[j] = (_Float16)Whh[j]; continue; }
    j -= S1;
    if (j < S2) { wih_h[j] = (_Float16)Wih[j]; continue; }
    j -= S2;
    if (j < S3) {
      int t = (int)(j >> 9), e = (int)(j & 511);
      xh[j] = (_Float16)emb[(long long)words[t] * EMBD + e];
      continue;
    }
    j -= S3;
    if (j < S4) { biasf[j] = bih[j] + bhh[j]; continue; }
    j -= S4;
    hg[j] = 0ull;   // tag 0, h = fp16 zeros
  }
}

/* ---------------- phase 1: xg = x @ Wih^T + bias, column-permuted ----------
   Source col n = g*1024 + r  (g = gate, r = h-row) stored at
   np = (r>>4)*64 + ((r>>2)&3)*16 + (r&3)*4 + g
   so that lane l of wave w in WG wg reads xg_p[s][wg*64 + w*16 + l]. */

__global__ __launch_bounds__(256) void xg_gemm(
    const _Float16* __restrict__ A, const _Float16* __restrict__ B,
    const float* __restrict__ biasf, float* __restrict__ C) {
  __shared__ char smem[2][2][8192];
  const int tid = threadIdx.x;
  const int lane = tid & 63;
  const int wid = tid >> 6;
  const int wy = wid >> 1, wx = wid & 1;
  const int tm = blockIdx.x * 128, tn = blockIdx.y * 128;

  floatx4 acc[4][4];
#pragma unroll
  for (int a = 0; a < 4; a++)
#pragma unroll
    for (int b = 0; b < 4; b++) acc[a][b] = (floatx4){0.f, 0.f, 0.f, 0.f};

  auto stage = [&](int buf, int kb) {
#pragma unroll
    for (int ii = 0; ii < 2; ii++) {
      int ci = tid + ii * 256;        // 0..511 chunks of 16B
      int r = ci >> 2, cs = ci & 3;
      int c = cs ^ (r & 3);           // inverse-swizzled source slot
      const _Float16* srcA = A + (long long)(tm + r) * EMBD + kb + c * 8;
      const _Float16* srcB = B + (long long)(tn + r) * EMBD + kb + c * 8;
      char* ldsA = &smem[buf][0][(ci & ~63) << 4];   // wave-uniform base
      char* ldsB = &smem[buf][1][(ci & ~63) << 4];
      stage16(srcA, ldsA);
      stage16(srcB, ldsB);
    }
  };

  stage(0, 0);
  __syncthreads();

  for (int t = 0; t < 16; t++) {
    int cur = t & 1;
    if (t < 15) stage(cur ^ 1, (t + 1) * 32);   // async, in flight during compute
    const char* As = smem[cur][0];
    const char* Bs = smem[cur][1];
    const int kc = lane >> 4;
    half8 af[4], bfr[4];
#pragma unroll
    for (int am = 0; am < 4; am++) {
      int r = wy * 64 + am * 16 + (lane & 15);
      af[am] = *(const half8*)(As + r * 64 + ((kc ^ (r & 3)) << 4));
    }
#pragma unroll
    for (int bn = 0; bn < 4; bn++) {
      int r = wx * 64 + bn * 16 + (lane & 15);
      bfr[bn] = *(const half8*)(Bs + r * 64 + ((kc ^ (r & 3)) << 4));
    }
#pragma unroll
    for (int am = 0; am < 4; am++)
#pragma unroll
      for (int bn = 0; bn < 4; bn++)
        acc[am][bn] = __builtin_amdgcn_mfma_f32_16x16x32_f16(af[am], bfr[bn], acc[am][bn], 0, 0, 0);
    __syncthreads();
  }

#pragma unroll
  for (int am = 0; am < 4; am++) {
    int mrow = tm + wy * 64 + am * 16 + (lane >> 4) * 4;
#pragma unroll
    for (int bn = 0; bn < 4; bn++) {
      int n = tn + wx * 64 + bn * 16 + (lane & 15);
      int r = n & 1023, g = n >> 10;
      int np = ((r >> 4) << 6) + (((r >> 2) & 3) << 4) + ((r & 3) << 2) + g;
      float bias = biasf[n];
#pragma unroll
      for (int rg = 0; rg < 4; rg++)
        C[(long long)(mrow + rg) * G4 + np] = acc[am][bn][rg] + bias;
    }
  }
}

/* ---------------- phase 2: persistent forward LSTM recurrence ----------------
   64 WGs x 256 threads (4 waves). WG wg owns h[wg*16 .. wg*16+16).
   Wave w: 16 gate-cols = {gate l&3, row wg*16 + w*4 + (l>>2)}, FULL K=1024.
   Sync design (R3): raw s_barrier (no vmcnt drain), ONE barrier/step with
   LDS hp double-buffer, 2-deep pipelined polling with counted vmcnt.
   Monotone tags make stale register reads harmless false-negatives. */

__global__ __launch_bounds__(256, 1) void lstm_fwd(
    const _Float16* __restrict__ Whh_h, const float* __restrict__ xg,
    u64* __restrict__ hg) {
  __shared__ u32 hp[2][512];    // double-buffered packed fp16 h
  const int tid = threadIdx.x;
  const int lane = tid & 63;
  const int w = tid >> 6;       // wave 0..3
  const int wg = blockIdx.x;
  const int n = lane & 15;
  const int kc = lane >> 4;

  // persistent B fragments: col n -> Whh row R, full K
  const int R = (n & 3) * HID + wg * 16 + w * 4 + (n >> 2);
  half8 Wb[32];
  {
    const _Float16* wr = Whh_h + (long long)R * HID + kc * 8;
#pragma unroll
    for (int kk = 0; kk < 32; kk++)
      Wb[kk] = *(const half8*)(wr + kk * 32);
  }

  u64* h0 = hg;
  u64* h1 = hg + 512;
  float c = 0.f;
  const float mulm = ((lane & 3) == 2) ? 2.f : 1.f;   // tanh lane: sigma(2x)
  const float addm = ((lane & 3) == 2) ? -1.f : 0.f;  // then 2t-1

  const float* xbase = xg + wg * 64 + w * 16 + lane;  // lanes < 16 use it
  float xv_cur = (lane < 16) ? xbase[0] : 0.f;
  float xv_nxt = 0.f;

  for (int s = 0; s < T_SEQ; s++) {
    const u64* p = ((s & 1) ? h1 : h0) + 2 * tid;
    u64* dst = (s & 1) ? h0 : h1;
    const u32 want = (u32)s;

    u64x2 va, vb, got;
    asm volatile("global_load_dwordx4 %0, %1, off sc1" : "=v"(va) : "v"(p) : "memory");
    asm volatile("global_load_dwordx4 %0, %1, off sc1" : "=v"(vb) : "v"(p) : "memory");
    // first check: slack 2 so we don't serialize on publish-store ack / xg
    // prefetch still in flight; a stale va just means a false-negative.
    asm volatile("s_waitcnt vmcnt(2)" ::: "memory");
    __builtin_amdgcn_sched_barrier(0);
    if (__all(((u32)(va.x >> 32) == want) & ((u32)(va.y >> 32) == want))) {
      got = va;
    } else {
      asm volatile("global_load_dwordx4 %0, %1, off sc1" : "=v"(va) : "v"(p) : "memory");
      for (;;) {
        asm volatile("s_waitcnt vmcnt(1)" ::: "memory");
        __builtin_amdgcn_sched_barrier(0);
        if (__all(((u32)(vb.x >> 32) == want) & ((u32)(vb.y >> 32) == want))) { got = vb; break; }
        asm volatile("global_load_dwordx4 %0, %1, off sc1" : "=v"(vb) : "v"(p) : "memory");
        asm volatile("s_waitcnt vmcnt(1)" ::: "memory");
        __builtin_amdgcn_sched_barrier(0);
        if (__all(((u32)(va.x >> 32) == want) & ((u32)(va.y >> 32) == want))) { got = va; break; }
        asm volatile("global_load_dwordx4 %0, %1, off sc1" : "=v"(va) : "v"(p) : "memory");
      }
    }

    // stage payloads to LDS (double-buffered by step parity)
    u32* hb = hp[s & 1];
    *reinterpret_cast<u64*>(&hb[2 * tid]) = ((u64)(u32)got.y << 32) | (u64)(u32)got.x;
    asm volatile("s_waitcnt lgkmcnt(0)" ::: "memory");
    __builtin_amdgcn_sched_barrier(0);
    __builtin_amdgcn_s_barrier();          // raw: no vmcnt drain

    // ---- matvec: 32 MFMAs, 4 interleaved chains; A = h broadcast ----
    floatx4 ac0 = (floatx4){0.f,0.f,0.f,0.f};
    floatx4 ac1 = (floatx4){0.f,0.f,0.f,0.f};
    floatx4 ac2 = (floatx4){0.f,0.f,0.f,0.f};
    floatx4 ac3 = (floatx4){0.f,0.f,0.f,0.f};
    const char* hh = (const char*)hb;
#pragma unroll
    for (int kb = 0; kb < 8; kb++) {
      half8 a0 = *(const half8*)(hh + (kb * 4 + 0) * 64 + kc * 16);
      half8 a1 = *(const half8*)(hh + (kb * 4 + 1) * 64 + kc * 16);
      half8 a2 = *(const half8*)(hh + (kb * 4 + 2) * 64 + kc * 16);
      half8 a3 = *(const half8*)(hh + (kb * 4 + 3) * 64 + kc * 16);
      ac0 = __builtin_amdgcn_mfma_f32_16x16x32_f16(a0, Wb[kb * 4 + 0], ac0, 0, 0, 0);
      ac1 = __builtin_amdgcn_mfma_f32_16x16x32_f16(a1, Wb[kb * 4 + 1], ac1, 0, 0, 0);
      ac2 = __builtin_amdgcn_mfma_f32_16x16x32_f16(a2, Wb[kb * 4 + 2], ac2, 0, 0, 0);
      ac3 = __builtin_amdgcn_mfma_f32_16x16x32_f16(a3, Wb[kb * 4 + 3], ac3, 0, 0, 0);
    }

    // drain stray poll loads + last xg prefetch; keep va/vb alive until here
    // so no pending writeback can land in a reused register.
    asm volatile("s_waitcnt vmcnt(0)" ::: "memory");
    __builtin_amdgcn_sched_barrier(0);
    asm volatile("" :: "v"(va), "v"(vb));

    // issue next step's xg prefetch (LLC-resident; used next iter post-MFMA)
    if (lane < 16) xv_nxt = xbase[(long long)((s + 1) & (T_SEQ - 1)) * G4];

    float gv = ac0[0] + ac1[0] + ac2[0] + ac3[0] + xv_cur;

    // branch-free activation: sigma for gates, tanh = 2*sigma(2x)-1 for g
    float e = __expf(-(mulm * gv));
    float t = frcp(1.f + e);
    float a = fmaf(t, mulm, addm);
    int base4 = lane & ~3;
    float i_ = __shfl(a, base4 + 0);
    float f_ = __shfl(a, base4 + 1);
    float g_ = __shfl(a, base4 + 2);
    float o_ = __shfl(a, base4 + 3);
    c = fmaf(f_, c, i_ * g_);            // valid in lanes 0,4,8,12
    float e2 = __expf(-2.f * c);
    float th = fmaf(2.f, frcp(1.f + e2), -1.f);
    float hn = o_ * th;

    union { _Float16 hx[2]; u32 u; } pk;
    pk.hx[0] = (_Float16)hn; pk.hx[1] = (_Float16)0.f;
    u32 bits = pk.u & 0xffffu;
    u32 nbr = (u32)__shfl((int)bits, lane | 4);   // lane0<-lane4, lane8<-lane12
    if (lane < 16 && (lane & 7) == 0) {
      u64 pkt = ((u64)(u32)(s + 1) << 32) | (u64)(bits | ((nbr & 0xffffu) << 16));
      __hip_atomic_store(&dst[wg * 8 + w * 2 + (lane >> 3)], pkt,
                         __ATOMIC_RELAXED, __HIP_MEMORY_SCOPE_AGENT);
    }
    xv_cur = xv_nxt;
    // no second barrier: hp is double-buffered; rewrite of this parity can
    // only happen after every thread passed the NEXT step's barrier.
  }
}

/* ---------------- phase 3: backward direction = ONE cell step on x[T-1] ------- */

__global__ __launch_bounds__(256) void bwd_gates(
    const float* __restrict__ Wihb, const float* __restrict__ emb,
    const int* __restrict__ words, const float* __restrict__ bihb,
    const float* __restrict__ bhhb, float* __restrict__ gb) {
  const int row = blockIdx.x * 4 + (threadIdx.x >> 6);
  const int lane = threadIdx.x & 63;
  const long long wl = words[T_SEQ - 1];
  const float* xr = emb + wl * EMBD;
  const float* wr = Wihb + (long long)row * EMBD;
  const int k0 = lane * 8;
  float s = 0.f;
#pragma unroll
  for (int j = 0; j < 8; j += 4) {
    float4 wv = *(const float4*)(wr + k0 + j);
    float4 xv = *(const float4*)(xr + k0 + j);
    s += wv.x * xv.x + wv.y * xv.y + wv.z * xv.z + wv.w * xv.w;
  }
#pragma unroll
  for (int m = 1; m < 64; m <<= 1) s += __shfl_xor(s, m);
  if (lane == 0) gb[row] = s + bihb[row] + bhhb[row];
}

/* ---------------- phase 4: backward activations + projection ---------------- */

__global__ __launch_bounds__(256) void final_k(
    const u64* __restrict__ hg, const float* __restrict__ gb,
    const float* __restrict__ Wp, const float* __restrict__ bp,
    float* __restrict__ out) {
  __shared__ float last[2 * HID];
  __shared__ float red[4];
  const int tid = threadIdx.x;
  // h_T sits in parity-0 buffer as 512 {tag, 2xfp16} packets
  for (int p = tid; p < 512; p += 256) {
    u32 b = (u32)hg[p];
    union { unsigned short s; _Float16 h; } lo, hi;
    lo.s = (unsigned short)(b & 0xffffu);
    hi.s = (unsigned short)(b >> 16);
    last[2 * p]     = (float)lo.h;
    last[2 * p + 1] = (float)hi.h;
  }
  for (int j = tid; j < HID; j += 256) {
    float i_ = fsigmoid(gb[j]);
    float g_ = ftanh(gb[2 * HID + j]);
    float o_ = fsigmoid(gb[3 * HID + j]);
    float cb = i_ * g_;                              // c0 = 0, f-gate irrelevant
    last[HID + j] = o_ * ftanh(cb);
  }
  __syncthreads();
  const int lane = tid & 63, wv = tid >> 6;
  for (int nn = 0; nn < 5; nn++) {
    float p = 0.f;
    for (int j = tid; j < 2 * HID; j += 256) p += last[j] * Wp[nn * 2 * HID + j];
#pragma unroll
    for (int m = 1; m < 64; m <<= 1) p += __shfl_xor(p, m);
    if (lane == 0) red[wv] = p;
    __syncthreads();
    if (tid == 0) out[nn] = red[0] + red[1] + red[2] + red[3] + bp[nn];
    __syncthreads();
  }
}

/* ---------------- launcher ---------------- */

extern "C" void kernel_launch(void* const* d_in, const int* in_sizes, int n_in,
                              void* d_out, int out_size, void* d_ws, size_t ws_size,
                              hipStream_t stream) {
  const int*   words = (const int*)d_in[0];
  const float* emb   = (const float*)d_in[1];
  const float* Wih_f = (const float*)d_in[2];
  const float* Whh_f = (const float*)d_in[3];
  const float* bih_f = (const float*)d_in[4];
  const float* bhh_f = (const float*)d_in[5];
  const float* Wih_b = (const float*)d_in[6];
  /* d_in[7] = Whh_b: unused — backward direction is a single step from zero state */
  const float* bih_b = (const float*)d_in[8];
  const float* bhh_b = (const float*)d_in[9];
  const float* Wp    = (const float*)d_in[10];
  const float* bp    = (const float*)d_in[11];
  float* out = (float*)d_out;

  char* ws = (char*)d_ws;
  float*    XG    = (float*)(ws);                    // [T,4H] f32, col-permuted: 64 MB
  _Float16* WHH   = (_Float16*)(ws + 67108864);      // [4H,H] fp16: 8 MB
  _Float16* WIH   = (_Float16*)(ws + 75497472);      // [4H,E] fp16: 4 MB
  _Float16* XH    = (_Float16*)(ws + 79691776);      // [T,E]  fp16: 4 MB
  u64*      HG    = (u64*)(ws + 83886080);           // 2 x 512 tagged h packets: 8 KB
  float*    GB    = (float*)(ws + 83902464);         // backward gates: 16 KB
  float*    BIASF = (float*)(ws + 83918848);         // bih_f + bhh_f: 16 KB

  prep_kernel<<<2048, 256, 0, stream>>>(Whh_f, Wih_f, emb, words, bih_f, bhh_f,
                                        WHH, WIH, XH, BIASF, HG);
  xg_gemm<<<dim3(32, 32), 256, 0, stream>>>(XH, WIH, BIASF, XG);
  lstm_fwd<<<NWG, 256, 0, stream>>>(WHH, XG, HG);
  bwd_gates<<<1024, 256, 0, stream>>>(Wih_b, emb, words, bih_b, bhh_b, GB);
  final_k<<<1, 256, 0, stream>>>(HG, GB, Wp, bp, out);
}